// Round 14
// baseline (315.218 us; speedup 1.0000x reference)
//
#include <hip/hip_runtime.h>
#include <hip/hip_bf16.h>
#include <hip/hip_fp16.h>
#include <math.h>

#define N_USERS 50000
#define N_ITEMS 50000
#define N_NODES 100000
#define DIM 64
#define BATCH 2048
#define SLOTS 4096

// graph-2 binning geometry
#define BROWS 128            // rows per bucket
#define NBUK 782             // ceil(N_NODES / BROWS)
#define CAPB 4096            // records per bucket region (4 sub-regions of 1024)
#define SUBCAP 1024          // per-sub-region capacity (mean 640, ~15 sigma headroom)
#define BCHUNK 8192          // edges per bin block -> 245 blocks
#define BINTHREADS 1024

// exp(2*dot) = exp2(dot * 2*log2(e)); folded into z1b at creation
#define TTL_PRESCALE 2.8853900817779268f

using frag_ab = __attribute__((ext_vector_type(8))) short;  // 8 bf16
using frag_cd = __attribute__((ext_vector_type(4))) float;  // 4 fp32
typedef unsigned long long u64;
typedef unsigned int u32;

// ---------------- helpers ----------------

__device__ __forceinline__ float wave_reduce_sum(float v) {
#pragma unroll
  for (int off = 32; off > 0; off >>= 1)
    v += __shfl_xor(v, off, 64);
  return v;
}

__device__ __forceinline__ const float* ego_row(const float* ue, const float* ie, int n) {
  return (n < N_USERS) ? (ue + (size_t)n * DIM) : (ie + (size_t)(n - N_USERS) * DIM);
}

__device__ __forceinline__ ushort f2bf(float x) {
  __hip_bfloat16 h = __float2bfloat16(x);
  return *(ushort*)&h;
}

__device__ __forceinline__ float bf2f(ushort u) {
  return __uint_as_float(((unsigned)u) << 16);
}

// guaranteed single-instruction native exp2 (v_exp_f32) — proven R10-R12
__device__ __forceinline__ float exp2_native(float x) {
  float y;
  asm volatile("v_exp_f32 %0, %1" : "=v"(y) : "v"(x));
  return y;
}

// ---------------- small setup kernels ----------------

__global__ void build_map_kernel(const int* __restrict__ nu, const int* __restrict__ ni,
                                 int* __restrict__ map) {
  int s = blockIdx.x * blockDim.x + threadIdx.x;
  if (s >= SLOTS) return;
  int n = (s < BATCH) ? nu[s] : (N_USERS + ni[s - BATCH]);
  map[n] = s;
}

// ---------------- graph 2 step 1: LDS-binned coarse scatter ----------------
__global__ __launch_bounds__(BINTHREADS) void bin_kernel(
    const int* __restrict__ rows, const int* __restrict__ cols,
    int* __restrict__ bcur, u32* __restrict__ rec, int nE) {
  __shared__ int lofs[NBUK];  // 3.1 KB
  int tid = threadIdx.x;
  int sub = blockIdx.x & 3;
  int e0 = blockIdx.x * BCHUNK;
  int nHere = nE - e0;
  if (nHere > BCHUNK) nHere = BCHUNK;

  for (int i = tid; i < NBUK; i += BINTHREADS) lofs[i] = 0;
  __syncthreads();

  for (int i = tid; i < nHere; i += BINTHREADS)
    atomicAdd(&lofs[rows[e0 + i] >> 7], 1);  // LDS atomic
  __syncthreads();

  for (int b = tid; b < NBUK; b += BINTHREADS) {
    int c = lofs[b];
    // padded counters: one (bucket,sub) counter per 64B line
    lofs[b] = c ? atomicAdd(&bcur[(b * 4 + sub) * 16], c) : 0;
  }
  __syncthreads();

  for (int i = tid; i < nHere; i += BINTHREADS) {
    int r = rows[e0 + i];  // re-read: range is L2-resident from pass 1
    int b = r >> 7;
    int p = atomicAdd(&lofs[b], 1);  // LDS cursor (offset within sub-region)
    if (p < SUBCAP)
      rec[((size_t)b << 12) + sub * SUBCAP + p] =
          ((u32)(r & 127) << 17) | (u32)cols[e0 + i];
  }
}

// ---------------- graph 2 step 2: per-bucket row sort ----------------
__global__ __launch_bounds__(256) void sort_kernel(
    const int* __restrict__ bcur, const u32* __restrict__ rec,
    u32* __restrict__ rec2, int* __restrict__ base, int* __restrict__ endv) {
  __shared__ int hist[BROWS];
  __shared__ int hcur[BROWS];
  int b = blockIdx.x;
  int tid = threadIdx.x;
  int cnt[4];
#pragma unroll
  for (int j = 0; j < 4; j++) {
    int c = bcur[(b * 4 + j) * 16];
    cnt[j] = (c < SUBCAP) ? c : SUBCAP;
  }
  size_t gb = (size_t)b << 12;

  if (tid < BROWS) hist[tid] = 0;
  __syncthreads();

  u32 myrec[CAPB / 256];
#pragma unroll
  for (int i = 0; i < CAPB / 256; i++) {
    int k = tid + i * 256;
    // sub = i>>2 is compile-time (256 divides 1024); validity = idx-in-sub < cnt
    u32 u = ((k & (SUBCAP - 1)) < cnt[i >> 2]) ? rec[gb + k] : ~0u;
    myrec[i] = u;
    if (u != ~0u) atomicAdd(&hist[(u >> 17) & 127], 1);
  }
  __syncthreads();

  int wave = tid >> 6, lane = tid & 63;
  if (wave == 0) {
    int v0 = hist[lane], v1 = hist[lane + 64];
    int s0 = v0, s1 = v1;
#pragma unroll
    for (int off = 1; off < 64; off <<= 1) {
      int t0 = __shfl_up(s0, off, 64);
      if (lane >= off) s0 += t0;
      int t1 = __shfl_up(s1, off, 64);
      if (lane >= off) s1 += t1;
    }
    int tot0 = __shfl(s0, 63, 64);
    int e0 = s0 - v0;            // exclusive offsets
    int e1 = tot0 + s1 - v1;
    hcur[lane] = e0;
    hcur[lane + 64] = e1;
    int gb32 = b * CAPB;
    int n0 = b * BROWS;
    if (n0 + lane < N_NODES) {
      base[n0 + lane] = gb32 + e0;
      endv[n0 + lane] = gb32 + e0 + v0;
    }
    if (n0 + lane + 64 < N_NODES) {
      base[n0 + lane + 64] = gb32 + e1;
      endv[n0 + lane + 64] = gb32 + e1 + v1;
    }
  }
  __syncthreads();

#pragma unroll
  for (int i = 0; i < CAPB / 256; i++) {
    u32 u = myrec[i];
    if (u != ~0u) {
      int rl = (u >> 17) & 127;
      int pos = atomicAdd(&hcur[rl], 1);  // scalar LDS atomic
      rec2[gb + pos] = u & 0x1FFFF;       // col only; row now implicit
    }
  }
}

// ego -> bf16 tables: xb (plain, for graph1) and xbp (premultiplied by dinv2[c];
// edge value dinv2[r]*dinv2[c] folds into the table + one row-scale at the end).
__global__ void ego2bf_kernel(const float* __restrict__ ue, const float* __restrict__ ie,
                              const int* __restrict__ base, const int* __restrict__ endv,
                              ushort* __restrict__ xb, ushort* __restrict__ xbp) {
  int t = blockIdx.x * blockDim.x + threadIdx.x;  // index of float4 group
  const int TOT = N_NODES * DIM / 4;
  if (t >= TOT) return;
  const int UH = N_USERS * DIM / 4;
  float4 f = (t < UH) ? ((const float4*)ue)[t] : ((const float4*)ie)[t - UH];
  ushort4 o;
  o.x = f2bf(f.x); o.y = f2bf(f.y); o.z = f2bf(f.z); o.w = f2bf(f.w);
  ((ushort4*)xb)[t] = o;
  int node = t >> 4;  // 16 float4-groups per 64-dim row
  int d = endv[node] - base[node];
  float dc = (d > 0) ? rsqrtf((float)d) : 0.f;
  ushort4 p;
  p.x = f2bf(f.x * dc); p.y = f2bf(f.y * dc); p.z = f2bf(f.z * dc); p.w = f2bf(f.w * dc);
  ((ushort4*)xbp)[t] = p;
}

// ---------------- graph 2 step 3: chase-free SpMM + normalize ----------------
// 2 edges per wave step: lane owns a dim PAIR (ushort2 = 4B/lane); half-wave 0
// processes even edges, half 1 odd. Cross-half combine = shfl_xor(32).
__global__ __launch_bounds__(256) void spmm_csr_norm_kernel(
    const int* __restrict__ base, const int* __restrict__ endv,
    const u32* __restrict__ rec2, const ushort* __restrict__ xbp,
    const float* __restrict__ ue, const float* __restrict__ ie,
    ushort* __restrict__ zallb) {
  int n = blockIdx.x * 4 + (threadIdx.x >> 6);
  if (n >= N_NODES) return;
  int lane = threadIdx.x & 63;
  int half = lane >> 5;   // 0: even edge indices, 1: odd
  int sl = lane & 31;     // dim pair {2sl, 2sl+1}
  int b = base[n];
  int d = endv[n] - b;
  const u32* rp = rec2 + b;
  float a0 = 0.f, a1 = 0.f;
  int k = half;
  for (; k + 6 < d; k += 8) {  // 4 edges per half = 8 edges per wave iter
    u32 c0 = rp[k], c1 = rp[k + 2], c2 = rp[k + 4], c3 = rp[k + 6];
    u32 u0 = *(const u32*)(xbp + ((size_t)c0 << 6) + 2 * sl);
    u32 u1 = *(const u32*)(xbp + ((size_t)c1 << 6) + 2 * sl);
    u32 u2 = *(const u32*)(xbp + ((size_t)c2 << 6) + 2 * sl);
    u32 u3 = *(const u32*)(xbp + ((size_t)c3 << 6) + 2 * sl);
    a0 += (__uint_as_float(u0 << 16) + __uint_as_float(u1 << 16)) +
          (__uint_as_float(u2 << 16) + __uint_as_float(u3 << 16));
    a1 += (__uint_as_float(u0 & 0xFFFF0000u) + __uint_as_float(u1 & 0xFFFF0000u)) +
          (__uint_as_float(u2 & 0xFFFF0000u) + __uint_as_float(u3 & 0xFFFF0000u));
  }
  for (; k < d; k += 2) {
    u32 c = rp[k];
    u32 u = *(const u32*)(xbp + ((size_t)c << 6) + 2 * sl);
    a0 += __uint_as_float(u << 16);
    a1 += __uint_as_float(u & 0xFFFF0000u);
  }
  // combine even/odd halves (after this both halves hold identical values)
  a0 += __shfl_xor(a0, 32, 64);
  a1 += __shfl_xor(a1, 32, 64);

  float dinv = (d > 0) ? rsqrtf((float)d) : 0.f;
  a0 *= dinv;
  a1 *= dinv;

  const float* eg = ego_row(ue, ie, n);
  float2 e2 = *(const float2*)(eg + 2 * sl);
  float w0 = 0.5f * (e2.x + a0);
  float w1 = 0.5f * (e2.y + a1);
  float ss = w0 * w0 + w1 * w1;
#pragma unroll
  for (int off = 16; off > 0; off >>= 1)  // 32-lane reduce (halves identical)
    ss += __shfl_xor(ss, off, 64);
  float inv = 1.f / fmaxf(sqrtf(ss), 1e-12f);
  if (half == 0) {
    ushort2 oz;
    oz.x = f2bf(w0 * inv);
    oz.y = f2bf(w1 * inv);
    *(ushort2*)(zallb + (size_t)n * DIM + 2 * sl) = oz;
  }
}

// ---------------- graph 1: fused filter + accumulate ----------------
__global__ __launch_bounds__(256) void graph1_fused_kernel(
    const int* __restrict__ rows, const int* __restrict__ cols,
    const float* __restrict__ vals, const int* __restrict__ map,
    const ushort* __restrict__ xb, float* __restrict__ z1acc, int nE) {
  __shared__ int lcount;
  __shared__ int hcol[256];
  __shared__ float hval[256];
  __shared__ int hslot[256];
  int tid = threadIdx.x;
  if (tid == 0) lcount = 0;
  __syncthreads();
  int e = blockIdx.x * 256 + tid;
  if (e < nE) {
    int r = rows[e];
    int s = map[r];
    if (s >= 0) {
      int pos = atomicAdd(&lcount, 1);  // LDS atomic - block-local
      hcol[pos] = cols[e];
      hval[pos] = vals[e];
      hslot[pos] = s;
    }
  }
  __syncthreads();
  int n = lcount;
  int wave = tid >> 6, lane = tid & 63;
  for (int k = wave; k < n; k += 4) {
    int c = hcol[k];
    float v = hval[k];
    int s = hslot[k];
    float x = bf2f(xb[(size_t)c * DIM + lane]);
    unsafeAtomicAdd(&z1acc[(size_t)s * DIM + lane], v * x);
  }
}

// z1 normalize (fp32) -> bf16 (PRESCALED by 2*log2e for the ttl exp2 fold);
// pos-dot stored per slot (plain store) -> folded in final_kernel, no atomics.
__global__ void gather1_kernel(const float* __restrict__ ue, const float* __restrict__ ie,
                               const int* __restrict__ nu, const int* __restrict__ ni,
                               const int* __restrict__ map, const float* __restrict__ z1acc,
                               const ushort* __restrict__ zallb, ushort* __restrict__ z1b,
                               float* __restrict__ posdot) {
  int s = blockIdx.x * 4 + (threadIdx.x >> 6);
  if (s >= SLOTS) return;
  int lane = threadIdx.x & 63;
  int n = (s < BATCH) ? nu[s] : (N_USERS + ni[s - BATCH]);
  int fs = map[n];
  const float* e = ego_row(ue, ie, n);
  float v = 0.5f * (e[lane] + z1acc[(size_t)fs * DIM + lane]);
  float ss = wave_reduce_sum(v * v);
  float z = v / fmaxf(sqrtf(ss), 1e-12f);
  z1b[(size_t)s * DIM + lane] = f2bf(z * TTL_PRESCALE);
  float dp = wave_reduce_sum(z * bf2f(zallb[(size_t)n * DIM + lane]));
  if (lane == 0) posdot[s] = dp;
}

// ---------------- ttl (bf16 MFMA, whole-strip LDS, barrier-free loop) -------
// R12-proven 512-thread / 8-wave configuration (VGPR 112, passing x3 rounds).
// ONLY change vs R12: strip->XCD affinity decode. bid = s%8 + 8*rb + 128*(s/8)
// (bijective; grid padded to 2048, 48 pad blocks exit uniformly). All 16
// blocks of a strip share bid%8 -> one XCD L2 -> strip fetched from HBM once.
#define TTL_STRIPS 125
#define TTL_CHUNKS 25
#define TTL_RB 16            // 4096 rows / 256 rows-per-block
__global__ __launch_bounds__(512) void ttl_mfma_kernel(const ushort* __restrict__ z1b,
                                                       const ushort* __restrict__ zallb,
                                                       float* __restrict__ partial) {
  __shared__ int4 sB[TTL_CHUNKS * 128];  // 51.2 KB: entire strip
  int bid = blockIdx.x;
  int strip = (bid & 7) + 8 * (bid >> 7);   // same-strip blocks share bid%8
  int rb = (bid >> 3) & 15;
  if (strip >= TTL_STRIPS) return;          // padded grid, block-uniform exit
  int tid = threadIdx.x;
  int wave = tid >> 6, lane = tid & 63;
  int r0 = rb * 256 + wave * 32;
  int side = (rb * 256) >> 11;  // rows 0..2047 users, 2048..4095 items
  const ushort* zs = zallb + (size_t)side * N_USERS * DIM;

  int m = lane & 15, q = lane >> 4;
  const ushort* ar0 = z1b + (size_t)(r0 + m) * DIM + q * 8;
  frag_ab a00 = *(const frag_ab*)ar0;
  frag_ab a01 = *(const frag_ab*)(ar0 + 32);
  const ushort* ar1 = ar0 + 16 * DIM;
  frag_ab a10 = *(const frag_ab*)ar1;
  frag_ab a11 = *(const frag_ab*)(ar1 + 32);

  int j0 = strip * (TTL_CHUNKS * 16);
  const char* bbase = (const char*)(zs + (size_t)j0 * DIM);  // strip rows contiguous

  // stage whole strip: 3200 x 16B pieces, swizzled dest (byte ^ ((row&7)<<4))
  for (int i = tid; i < TTL_CHUNKS * 128; i += 512) {
    int off = i * 16;
    int swz = off ^ (((off >> 7) & 7) << 4);
    *(int4*)((char*)sB + swz) = *(const int4*)(bbase + off);
  }
  __syncthreads();  // the only barrier

  // swizzled LDS read offsets for this lane
  int swl = (m & 7) << 4;
  int o0 = (m * 128 + q * 16) ^ swl;
  int o1 = (m * 128 + 64 + q * 16) ^ swl;

  float racc[8] = {0.f, 0.f, 0.f, 0.f, 0.f, 0.f, 0.f, 0.f};

  for (int c = 0; c < TTL_CHUNKS; c++) {
    const char* sb = (const char*)sB + c * 2048;
    frag_ab b0 = *(const frag_ab*)(sb + o0);
    frag_ab b1 = *(const frag_ab*)(sb + o1);
    frag_cd acc0 = {}, acc1 = {};
    acc0 = __builtin_amdgcn_mfma_f32_16x16x32_bf16(a00, b0, acc0, 0, 0, 0);
    acc0 = __builtin_amdgcn_mfma_f32_16x16x32_bf16(a01, b1, acc0, 0, 0, 0);
    acc1 = __builtin_amdgcn_mfma_f32_16x16x32_bf16(a10, b0, acc1, 0, 0, 0);
    acc1 = __builtin_amdgcn_mfma_f32_16x16x32_bf16(a11, b1, acc1, 0, 0, 0);
#pragma unroll
    for (int r = 0; r < 4; r++) {
      racc[r] += exp2_native(acc0[r]);
      racc[4 + r] += exp2_native(acc1[r]);
    }
  }

  // C layout: col(=zall j) = lane&15, row(=z1 row) = q*4+reg. Reduce over the
  // 16 j-lanes. Plain stores: (strip, row) owned by exactly this block.
  float* pw = partial + (size_t)strip * SLOTS;
#pragma unroll
  for (int h = 0; h < 2; h++) {
#pragma unroll
    for (int r = 0; r < 4; r++) {
      float v = racc[h * 4 + r];
      v += __shfl_xor(v, 1, 64);
      v += __shfl_xor(v, 2, 64);
      v += __shfl_xor(v, 4, 64);
      v += __shfl_xor(v, 8, 64);
      if (m == 0) pw[r0 + h * 16 + q * 4 + r] = v;
    }
  }
}

// out += sum_r [ 0.5*log(sum_s partial[s][r]) - posdot[r] ]; coalesced: lane=row
__global__ void final_kernel(const float* __restrict__ partial,
                             const float* __restrict__ posdot,
                             float* __restrict__ out) {
  int row = blockIdx.x * blockDim.x + threadIdx.x;  // 16 x 256 = 4096
  float t = 0.f;
  for (int s = 0; s < TTL_STRIPS; s++)
    t += partial[(size_t)s * SLOTS + row];
  float v = 0.5f * logf(t) - posdot[row];
  v = wave_reduce_sum(v);
  if ((threadIdx.x & 63) == 0) atomicAdd(out, v);
}

// ---------------- launch ----------------

extern "C" void kernel_launch(void* const* d_in, const int* in_sizes, int n_in,
                              void* d_out, int out_size, void* d_ws, size_t ws_size,
                              hipStream_t stream) {
  const float* ue = (const float*)d_in[0];
  const float* ie = (const float*)d_in[1];
  const int* rows1 = (const int*)d_in[2];
  const int* cols1 = (const int*)d_in[3];
  const float* vals1 = (const float*)d_in[4];
  const int* rows2 = (const int*)d_in[5];
  const int* cols2 = (const int*)d_in[6];
  const int* nu = (const int*)d_in[8];
  const int* ni = (const int*)d_in[9];
  int nE1 = in_sizes[2], nE2 = in_sizes[5];

  // workspace carve-out (256B aligned), ~70 MB
  char* ws = (char*)d_ws;
  size_t o = 0;
  auto carve = [&](size_t bytes) {
    char* p = ws + o;
    o += (bytes + 255) & ~(size_t)255;
    return p;
  };
  int* map = (int*)carve(N_NODES * 4);
  float* z1acc = (float*)carve((size_t)SLOTS * DIM * 4);
  float* partial = (float*)carve((size_t)TTL_STRIPS * SLOTS * 4);  // 2 MB
  float* posdot = (float*)carve(SLOTS * 4);
  ushort* zallb = (ushort*)carve((size_t)N_NODES * DIM * 2);
  ushort* z1b = (ushort*)carve((size_t)SLOTS * DIM * 2);
  ushort* xb = (ushort*)carve((size_t)N_NODES * DIM * 2);
  ushort* xbp = (ushort*)carve((size_t)N_NODES * DIM * 2);
  int* bcur = (int*)carve((size_t)NBUK * 4 * 16 * 4);  // 4 subs x padded 64B
  int* base = (int*)carve(N_NODES * 4);
  int* endv = (int*)carve(N_NODES * 4);
  u32* rec = (u32*)carve((size_t)NBUK * CAPB * 4);
  u32* rec2 = (u32*)carve((size_t)NBUK * CAPB * 4);
  float* out = (float*)d_out;

  hipMemsetAsync(map, 0xFF, N_NODES * 4, stream);  // -1
  hipMemsetAsync(bcur, 0, (size_t)NBUK * 4 * 16 * 4, stream);
  hipMemsetAsync(z1acc, 0, (size_t)SLOTS * DIM * 4, stream);
  hipMemsetAsync(out, 0, sizeof(float), stream);

  build_map_kernel<<<16, 256, 0, stream>>>(nu, ni, map);
  // graph-2: coarse bin (4 sub-allocators) -> per-bucket row sort -> SpMM
  bin_kernel<<<(nE2 + BCHUNK - 1) / BCHUNK, BINTHREADS, 0, stream>>>(rows2, cols2, bcur, rec, nE2);
  sort_kernel<<<NBUK, 256, 0, stream>>>(bcur, rec, rec2, base, endv);
  ego2bf_kernel<<<(N_NODES * DIM / 4 + 255) / 256, 256, 0, stream>>>(ue, ie, base, endv, xb, xbp);
  spmm_csr_norm_kernel<<<(N_NODES + 3) / 4, 256, 0, stream>>>(base, endv, rec2, xbp, ue, ie, zallb);
  graph1_fused_kernel<<<(nE1 + 255) / 256, 256, 0, stream>>>(rows1, cols1, vals1, map, xb, z1acc, nE1);
  gather1_kernel<<<SLOTS / 4, 256, 0, stream>>>(ue, ie, nu, ni, map, z1acc, zallb, z1b, posdot);
  ttl_mfma_kernel<<<2048, 512, 0, stream>>>(z1b, zallb, partial);
  final_kernel<<<SLOTS / 256, 256, 0, stream>>>(partial, posdot, out);
}

// Round 15
// 302.816 us; speedup vs baseline: 1.0410x; 1.0410x over previous
//
#include <hip/hip_runtime.h>
#include <hip/hip_bf16.h>
#include <hip/hip_fp16.h>
#include <math.h>

#define N_USERS 50000
#define N_ITEMS 50000
#define N_NODES 100000
#define DIM 64
#define BATCH 2048
#define SLOTS 4096

// graph-2 binning geometry
#define BROWS 128            // rows per bucket
#define NBUK 782             // ceil(N_NODES / BROWS)
#define CAPB 4096            // records per bucket region (4 sub-regions of 1024)
#define SUBCAP 1024          // per-sub-region capacity (mean 640, ~15 sigma headroom)
#define BCHUNK 8192          // edges per bin block -> 245 bin blocks
#define BINTHREADS 1024
#define XB_BLOCKS 1563       // ceil(N_NODES*DIM/4 / 1024) xb-conversion blocks

// exp(2*dot) = exp2(dot * 2*log2(e)); folded into z1b at creation
#define TTL_PRESCALE 2.8853900817779268f

#define SPMM_BLOCKS (N_NODES / 4)  // 25000

using frag_ab = __attribute__((ext_vector_type(8))) short;  // 8 bf16
using frag_cd = __attribute__((ext_vector_type(4))) float;  // 4 fp32
typedef unsigned long long u64;
typedef unsigned int u32;

// ---------------- helpers ----------------

__device__ __forceinline__ float wave_reduce_sum(float v) {
#pragma unroll
  for (int off = 32; off > 0; off >>= 1)
    v += __shfl_xor(v, off, 64);
  return v;
}

__device__ __forceinline__ const float* ego_row(const float* ue, const float* ie, int n) {
  return (n < N_USERS) ? (ue + (size_t)n * DIM) : (ie + (size_t)(n - N_USERS) * DIM);
}

__device__ __forceinline__ ushort f2bf(float x) {
  __hip_bfloat16 h = __float2bfloat16(x);
  return *(ushort*)&h;
}

__device__ __forceinline__ float bf2f(ushort u) {
  return __uint_as_float(((unsigned)u) << 16);
}

// guaranteed single-instruction native exp2 (v_exp_f32) — proven R10-R14
__device__ __forceinline__ float exp2_native(float x) {
  float y;
  asm volatile("v_exp_f32 %0, %1" : "=v"(y) : "v"(x));
  return y;
}

// ---------------- small setup kernels ----------------

__global__ void build_map_kernel(const int* __restrict__ nu, const int* __restrict__ ni,
                                 int* __restrict__ map) {
  int s = blockIdx.x * blockDim.x + threadIdx.x;
  if (s >= SLOTS) return;
  int n = (s < BATCH) ? nu[s] : (N_USERS + ni[s - BATCH]);
  map[n] = s;
}

// ---------------- graph 2 step 1: LDS-binned scatter + fused xb convert ----
// Blocks [0,nBin): edge binning (R12-proven 4-sub-allocator form).
// Blocks [nBin, nBin+XB_BLOCKS): ego -> bf16 xb table (independent work,
// overlapped with binning instead of a separate serial kernel).
__global__ __launch_bounds__(BINTHREADS) void bin_xb_kernel(
    const int* __restrict__ rows, const int* __restrict__ cols,
    const float* __restrict__ ue, const float* __restrict__ ie,
    int* __restrict__ bcur, u32* __restrict__ rec, ushort* __restrict__ xb,
    int nE, int nBin) {
  if ((int)blockIdx.x >= nBin) {  // block-uniform branch: xb conversion
    int t = (blockIdx.x - nBin) * BINTHREADS + threadIdx.x;
    const int TOT = N_NODES * DIM / 4;
    if (t < TOT) {
      const int UH = N_USERS * DIM / 4;
      float4 f = (t < UH) ? ((const float4*)ue)[t] : ((const float4*)ie)[t - UH];
      ushort4 o;
      o.x = f2bf(f.x); o.y = f2bf(f.y); o.z = f2bf(f.z); o.w = f2bf(f.w);
      ((ushort4*)xb)[t] = o;
    }
    return;
  }

  __shared__ int lofs[NBUK];  // 3.1 KB
  int tid = threadIdx.x;
  int sub = blockIdx.x & 3;
  int e0 = blockIdx.x * BCHUNK;
  int nHere = nE - e0;
  if (nHere > BCHUNK) nHere = BCHUNK;

  for (int i = tid; i < NBUK; i += BINTHREADS) lofs[i] = 0;
  __syncthreads();

  for (int i = tid; i < nHere; i += BINTHREADS)
    atomicAdd(&lofs[rows[e0 + i] >> 7], 1);  // LDS atomic
  __syncthreads();

  for (int b = tid; b < NBUK; b += BINTHREADS) {
    int c = lofs[b];
    // padded counters: one (bucket,sub) counter per 64B line
    lofs[b] = c ? atomicAdd(&bcur[(b * 4 + sub) * 16], c) : 0;
  }
  __syncthreads();

  for (int i = tid; i < nHere; i += BINTHREADS) {
    int r = rows[e0 + i];  // re-read: range is L2-resident from pass 1
    int b = r >> 7;
    int p = atomicAdd(&lofs[b], 1);  // LDS cursor (offset within sub-region)
    if (p < SUBCAP)
      rec[((size_t)b << 12) + sub * SUBCAP + p] =
          ((u32)(r & 127) << 17) | (u32)cols[e0 + i];
  }
}

// ---------------- graph 2 step 2: per-bucket row sort + fused xbp ----------
// R12-proven sort; appended phase: premultiply this bucket's 128 xb rows by
// rsqrt(deg) (degrees already in LDS hist[]) -> xbp. Replaces the separate
// ego2bf kernel (serial ~10us) with ~16KB of streaming per block.
__global__ __launch_bounds__(256) void sort_kernel(
    const int* __restrict__ bcur, const u32* __restrict__ rec,
    u32* __restrict__ rec2, int* __restrict__ base, int* __restrict__ endv,
    const ushort* __restrict__ xb, ushort* __restrict__ xbp) {
  __shared__ int hist[BROWS];
  __shared__ int hcur[BROWS];
  int b = blockIdx.x;
  int tid = threadIdx.x;
  int cnt[4];
#pragma unroll
  for (int j = 0; j < 4; j++) {
    int c = bcur[(b * 4 + j) * 16];
    cnt[j] = (c < SUBCAP) ? c : SUBCAP;
  }
  size_t gb = (size_t)b << 12;

  if (tid < BROWS) hist[tid] = 0;
  __syncthreads();

  u32 myrec[CAPB / 256];
#pragma unroll
  for (int i = 0; i < CAPB / 256; i++) {
    int k = tid + i * 256;
    // sub = i>>2 is compile-time (256 divides 1024); validity = idx-in-sub < cnt
    u32 u = ((k & (SUBCAP - 1)) < cnt[i >> 2]) ? rec[gb + k] : ~0u;
    myrec[i] = u;
    if (u != ~0u) atomicAdd(&hist[(u >> 17) & 127], 1);
  }
  __syncthreads();

  int wave = tid >> 6, lane = tid & 63;
  if (wave == 0) {
    int v0 = hist[lane], v1 = hist[lane + 64];
    int s0 = v0, s1 = v1;
#pragma unroll
    for (int off = 1; off < 64; off <<= 1) {
      int t0 = __shfl_up(s0, off, 64);
      if (lane >= off) s0 += t0;
      int t1 = __shfl_up(s1, off, 64);
      if (lane >= off) s1 += t1;
    }
    int tot0 = __shfl(s0, 63, 64);
    int e0 = s0 - v0;            // exclusive offsets
    int e1 = tot0 + s1 - v1;
    hcur[lane] = e0;
    hcur[lane + 64] = e1;
    int gb32 = b * CAPB;
    int n0 = b * BROWS;
    if (n0 + lane < N_NODES) {
      base[n0 + lane] = gb32 + e0;
      endv[n0 + lane] = gb32 + e0 + v0;
    }
    if (n0 + lane + 64 < N_NODES) {
      base[n0 + lane + 64] = gb32 + e1;
      endv[n0 + lane + 64] = gb32 + e1 + v1;
    }
  }
  __syncthreads();

#pragma unroll
  for (int i = 0; i < CAPB / 256; i++) {
    u32 u = myrec[i];
    if (u != ~0u) {
      int rl = (u >> 17) & 127;
      int pos = atomicAdd(&hcur[rl], 1);  // scalar LDS atomic
      rec2[gb + pos] = u & 0x1FFFF;       // col only; row now implicit
    }
  }

  // fused xbp phase (independent of scatter; hist[] is stable counts).
  // thread t: row r = t>>1, 32 elems starting at (t&1)*32.
  int r = tid >> 1;
  int n = b * BROWS + r;
  if (n < N_NODES) {
    int dg = hist[r];
    float dc = (dg > 0) ? rsqrtf((float)dg) : 0.f;
    const ushort4* src = (const ushort4*)(xb + (size_t)n * DIM + (tid & 1) * 32);
    ushort4* dst = (ushort4*)(xbp + (size_t)n * DIM + (tid & 1) * 32);
#pragma unroll
    for (int j = 0; j < 8; j++) {
      ushort4 v = src[j];
      ushort4 p;
      p.x = f2bf(bf2f(v.x) * dc);
      p.y = f2bf(bf2f(v.y) * dc);
      p.z = f2bf(bf2f(v.z) * dc);
      p.w = f2bf(bf2f(v.w) * dc);
      dst[j] = p;
    }
  }
}

// ---------------- fused: graph-2 SpMM+normalize  ||  graph-1 accumulate ----
// Blocks [0, SPMM_BLOCKS): R12-proven 2-edge spmm (one wave per row).
// Blocks [SPMM_BLOCKS, +g1Blocks): R5-proven graph1 filter+accumulate.
// Independent work fused into one launch: graph1's ~20us overlaps spmm's
// memory stalls (spmm: VALUBusy 51%, HBM 22% -> plenty of idle to absorb).
__global__ __launch_bounds__(256) void spmm_graph1_kernel(
    const int* __restrict__ base, const int* __restrict__ endv,
    const u32* __restrict__ rec2, const ushort* __restrict__ xbp,
    const float* __restrict__ ue, const float* __restrict__ ie,
    ushort* __restrict__ zallb,
    const int* __restrict__ rows1, const int* __restrict__ cols1,
    const float* __restrict__ vals1, const int* __restrict__ map,
    const ushort* __restrict__ xb, float* __restrict__ z1acc, int nE1) {
  __shared__ int lcount;
  __shared__ int hcol[256];
  __shared__ float hval[256];
  __shared__ int hslot[256];
  int bid = blockIdx.x;
  int tid = threadIdx.x;

  if (bid >= SPMM_BLOCKS) {  // ---- graph1 part (block-uniform branch) ----
    if (tid == 0) lcount = 0;
    __syncthreads();
    int e = (bid - SPMM_BLOCKS) * 256 + tid;
    if (e < nE1) {
      int r = rows1[e];
      int s = map[r];
      if (s >= 0) {
        int pos = atomicAdd(&lcount, 1);  // LDS atomic - block-local
        hcol[pos] = cols1[e];
        hval[pos] = vals1[e];
        hslot[pos] = s;
      }
    }
    __syncthreads();
    int cnt = lcount;
    int wave = tid >> 6, lane = tid & 63;
    for (int k = wave; k < cnt; k += 4) {
      int c = hcol[k];
      float v = hval[k];
      int s = hslot[k];
      float x = bf2f(xb[(size_t)c * DIM + lane]);
      unsafeAtomicAdd(&z1acc[(size_t)s * DIM + lane], v * x);
    }
    return;
  }

  // ---- spmm part ----
  int n = bid * 4 + (tid >> 6);
  if (n >= N_NODES) return;
  int lane = tid & 63;
  int half = lane >> 5;   // 0: even edge indices, 1: odd
  int sl = lane & 31;     // dim pair {2sl, 2sl+1}
  int b = base[n];
  int d = endv[n] - b;
  const u32* rp = rec2 + b;
  float a0 = 0.f, a1 = 0.f;
  int k = half;
  for (; k + 6 < d; k += 8) {  // 4 edges per half = 8 edges per wave iter
    u32 c0 = rp[k], c1 = rp[k + 2], c2 = rp[k + 4], c3 = rp[k + 6];
    u32 u0 = *(const u32*)(xbp + ((size_t)c0 << 6) + 2 * sl);
    u32 u1 = *(const u32*)(xbp + ((size_t)c1 << 6) + 2 * sl);
    u32 u2 = *(const u32*)(xbp + ((size_t)c2 << 6) + 2 * sl);
    u32 u3 = *(const u32*)(xbp + ((size_t)c3 << 6) + 2 * sl);
    a0 += (__uint_as_float(u0 << 16) + __uint_as_float(u1 << 16)) +
          (__uint_as_float(u2 << 16) + __uint_as_float(u3 << 16));
    a1 += (__uint_as_float(u0 & 0xFFFF0000u) + __uint_as_float(u1 & 0xFFFF0000u)) +
          (__uint_as_float(u2 & 0xFFFF0000u) + __uint_as_float(u3 & 0xFFFF0000u));
  }
  for (; k < d; k += 2) {
    u32 c = rp[k];
    u32 u = *(const u32*)(xbp + ((size_t)c << 6) + 2 * sl);
    a0 += __uint_as_float(u << 16);
    a1 += __uint_as_float(u & 0xFFFF0000u);
  }
  // combine even/odd halves (after this both halves hold identical values)
  a0 += __shfl_xor(a0, 32, 64);
  a1 += __shfl_xor(a1, 32, 64);

  float dinv = (d > 0) ? rsqrtf((float)d) : 0.f;
  a0 *= dinv;
  a1 *= dinv;

  const float* eg = ego_row(ue, ie, n);
  float2 e2 = *(const float2*)(eg + 2 * sl);
  float w0 = 0.5f * (e2.x + a0);
  float w1 = 0.5f * (e2.y + a1);
  float ss = w0 * w0 + w1 * w1;
#pragma unroll
  for (int off = 16; off > 0; off >>= 1)  // 32-lane reduce (halves identical)
    ss += __shfl_xor(ss, off, 64);
  float inv = 1.f / fmaxf(sqrtf(ss), 1e-12f);
  if (half == 0) {
    ushort2 oz;
    oz.x = f2bf(w0 * inv);
    oz.y = f2bf(w1 * inv);
    *(ushort2*)(zallb + (size_t)n * DIM + 2 * sl) = oz;
  }
}

// z1 normalize (fp32) -> bf16 (PRESCALED by 2*log2e for the ttl exp2 fold);
// pos-dot stored per slot (plain store) -> folded in final_kernel, no atomics.
__global__ void gather1_kernel(const float* __restrict__ ue, const float* __restrict__ ie,
                               const int* __restrict__ nu, const int* __restrict__ ni,
                               const int* __restrict__ map, const float* __restrict__ z1acc,
                               const ushort* __restrict__ zallb, ushort* __restrict__ z1b,
                               float* __restrict__ posdot) {
  int s = blockIdx.x * 4 + (threadIdx.x >> 6);
  if (s >= SLOTS) return;
  int lane = threadIdx.x & 63;
  int n = (s < BATCH) ? nu[s] : (N_USERS + ni[s - BATCH]);
  int fs = map[n];
  const float* e = ego_row(ue, ie, n);
  float v = 0.5f * (e[lane] + z1acc[(size_t)fs * DIM + lane]);
  float ss = wave_reduce_sum(v * v);
  float z = v / fmaxf(sqrtf(ss), 1e-12f);
  z1b[(size_t)s * DIM + lane] = f2bf(z * TTL_PRESCALE);
  float dp = wave_reduce_sum(z * bf2f(zallb[(size_t)n * DIM + lane]));
  if (lane == 0) posdot[s] = dp;
}

// ---------------- ttl (bf16 MFMA, whole-strip LDS, barrier-free loop) -------
// R14-proven 512-thread / 8-wave configuration, strip->XCD affinity decode.
#define TTL_STRIPS 125
#define TTL_CHUNKS 25
#define TTL_RB 16            // 4096 rows / 256 rows-per-block
__global__ __launch_bounds__(512) void ttl_mfma_kernel(const ushort* __restrict__ z1b,
                                                       const ushort* __restrict__ zallb,
                                                       float* __restrict__ partial) {
  __shared__ int4 sB[TTL_CHUNKS * 128];  // 51.2 KB: entire strip
  int bid = blockIdx.x;
  int strip = (bid & 7) + 8 * (bid >> 7);   // same-strip blocks share bid%8
  int rb = (bid >> 3) & 15;
  if (strip >= TTL_STRIPS) return;          // padded grid, block-uniform exit
  int tid = threadIdx.x;
  int wave = tid >> 6, lane = tid & 63;
  int r0 = rb * 256 + wave * 32;
  int side = (rb * 256) >> 11;  // rows 0..2047 users, 2048..4095 items
  const ushort* zs = zallb + (size_t)side * N_USERS * DIM;

  int m = lane & 15, q = lane >> 4;
  const ushort* ar0 = z1b + (size_t)(r0 + m) * DIM + q * 8;
  frag_ab a00 = *(const frag_ab*)ar0;
  frag_ab a01 = *(const frag_ab*)(ar0 + 32);
  const ushort* ar1 = ar0 + 16 * DIM;
  frag_ab a10 = *(const frag_ab*)ar1;
  frag_ab a11 = *(const frag_ab*)(ar1 + 32);

  int j0 = strip * (TTL_CHUNKS * 16);
  const char* bbase = (const char*)(zs + (size_t)j0 * DIM);  // strip rows contiguous

  // stage whole strip: 3200 x 16B pieces, swizzled dest (byte ^ ((row&7)<<4))
  for (int i = tid; i < TTL_CHUNKS * 128; i += 512) {
    int off = i * 16;
    int swz = off ^ (((off >> 7) & 7) << 4);
    *(int4*)((char*)sB + swz) = *(const int4*)(bbase + off);
  }
  __syncthreads();  // the only barrier

  // swizzled LDS read offsets for this lane
  int swl = (m & 7) << 4;
  int o0 = (m * 128 + q * 16) ^ swl;
  int o1 = (m * 128 + 64 + q * 16) ^ swl;

  float racc[8] = {0.f, 0.f, 0.f, 0.f, 0.f, 0.f, 0.f, 0.f};

  for (int c = 0; c < TTL_CHUNKS; c++) {
    const char* sb = (const char*)sB + c * 2048;
    frag_ab b0 = *(const frag_ab*)(sb + o0);
    frag_ab b1 = *(const frag_ab*)(sb + o1);
    frag_cd acc0 = {}, acc1 = {};
    acc0 = __builtin_amdgcn_mfma_f32_16x16x32_bf16(a00, b0, acc0, 0, 0, 0);
    acc0 = __builtin_amdgcn_mfma_f32_16x16x32_bf16(a01, b1, acc0, 0, 0, 0);
    acc1 = __builtin_amdgcn_mfma_f32_16x16x32_bf16(a10, b0, acc1, 0, 0, 0);
    acc1 = __builtin_amdgcn_mfma_f32_16x16x32_bf16(a11, b1, acc1, 0, 0, 0);
#pragma unroll
    for (int r = 0; r < 4; r++) {
      racc[r] += exp2_native(acc0[r]);
      racc[4 + r] += exp2_native(acc1[r]);
    }
  }

  // C layout: col(=zall j) = lane&15, row(=z1 row) = q*4+reg. Reduce over the
  // 16 j-lanes. Plain stores: (strip, row) owned by exactly this block.
  float* pw = partial + (size_t)strip * SLOTS;
#pragma unroll
  for (int h = 0; h < 2; h++) {
#pragma unroll
    for (int r = 0; r < 4; r++) {
      float v = racc[h * 4 + r];
      v += __shfl_xor(v, 1, 64);
      v += __shfl_xor(v, 2, 64);
      v += __shfl_xor(v, 4, 64);
      v += __shfl_xor(v, 8, 64);
      if (m == 0) pw[r0 + h * 16 + q * 4 + r] = v;
    }
  }
}

// out += sum_r [ 0.5*log(sum_s partial[s][r]) - posdot[r] ]; coalesced: lane=row
__global__ void final_kernel(const float* __restrict__ partial,
                             const float* __restrict__ posdot,
                             float* __restrict__ out) {
  int row = blockIdx.x * blockDim.x + threadIdx.x;  // 16 x 256 = 4096
  float t = 0.f;
  for (int s = 0; s < TTL_STRIPS; s++)
    t += partial[(size_t)s * SLOTS + row];
  float v = 0.5f * logf(t) - posdot[row];
  v = wave_reduce_sum(v);
  if ((threadIdx.x & 63) == 0) atomicAdd(out, v);
}

// ---------------- launch ----------------

extern "C" void kernel_launch(void* const* d_in, const int* in_sizes, int n_in,
                              void* d_out, int out_size, void* d_ws, size_t ws_size,
                              hipStream_t stream) {
  const float* ue = (const float*)d_in[0];
  const float* ie = (const float*)d_in[1];
  const int* rows1 = (const int*)d_in[2];
  const int* cols1 = (const int*)d_in[3];
  const float* vals1 = (const float*)d_in[4];
  const int* rows2 = (const int*)d_in[5];
  const int* cols2 = (const int*)d_in[6];
  const int* nu = (const int*)d_in[8];
  const int* ni = (const int*)d_in[9];
  int nE1 = in_sizes[2], nE2 = in_sizes[5];

  // workspace carve-out (256B aligned), ~70 MB
  char* ws = (char*)d_ws;
  size_t o = 0;
  auto carve = [&](size_t bytes) {
    char* p = ws + o;
    o += (bytes + 255) & ~(size_t)255;
    return p;
  };
  int* map = (int*)carve(N_NODES * 4);
  float* z1acc = (float*)carve((size_t)SLOTS * DIM * 4);
  float* partial = (float*)carve((size_t)TTL_STRIPS * SLOTS * 4);  // 2 MB
  float* posdot = (float*)carve(SLOTS * 4);
  ushort* zallb = (ushort*)carve((size_t)N_NODES * DIM * 2);
  ushort* z1b = (ushort*)carve((size_t)SLOTS * DIM * 2);
  ushort* xb = (ushort*)carve((size_t)N_NODES * DIM * 2);
  ushort* xbp = (ushort*)carve((size_t)N_NODES * DIM * 2);
  int* bcur = (int*)carve((size_t)NBUK * 4 * 16 * 4);  // 4 subs x padded 64B
  int* base = (int*)carve(N_NODES * 4);
  int* endv = (int*)carve(N_NODES * 4);
  u32* rec = (u32*)carve((size_t)NBUK * CAPB * 4);
  u32* rec2 = (u32*)carve((size_t)NBUK * CAPB * 4);
  float* out = (float*)d_out;

  hipMemsetAsync(map, 0xFF, N_NODES * 4, stream);  // -1
  hipMemsetAsync(bcur, 0, (size_t)NBUK * 4 * 16 * 4, stream);
  hipMemsetAsync(z1acc, 0, (size_t)SLOTS * DIM * 4, stream);
  hipMemsetAsync(out, 0, sizeof(float), stream);

  build_map_kernel<<<16, 256, 0, stream>>>(nu, ni, map);
  // graph-2: bin (+fused xb convert) -> sort (+fused xbp) -> spmm||graph1
  int nBin = (nE2 + BCHUNK - 1) / BCHUNK;
  bin_xb_kernel<<<nBin + XB_BLOCKS, BINTHREADS, 0, stream>>>(
      rows2, cols2, ue, ie, bcur, rec, xb, nE2, nBin);
  sort_kernel<<<NBUK, 256, 0, stream>>>(bcur, rec, rec2, base, endv, xb, xbp);
  int g1Blocks = (nE1 + 255) / 256;
  spmm_graph1_kernel<<<SPMM_BLOCKS + g1Blocks, 256, 0, stream>>>(
      base, endv, rec2, xbp, ue, ie, zallb, rows1, cols1, vals1, map, xb, z1acc, nE1);
  gather1_kernel<<<SLOTS / 4, 256, 0, stream>>>(ue, ie, nu, ni, map, z1acc, zallb, z1b, posdot);
  ttl_mfma_kernel<<<2048, 512, 0, stream>>>(z1b, zallb, partial);
  final_kernel<<<SLOTS / 256, 256, 0, stream>>>(partial, posdot, out);
}